// Round 1
// baseline (301.536 us; speedup 1.0000x reference)
//
#include <hip/hip_runtime.h>

// SoftDtwRkdDistance: B=32, T=96, D=128, f32 in, scalar f32 out.
// dtw[p] for all 1024 pairs x {student, teacher}, then normalized smooth-L1.

constexpr int TT = 96;
constexpr int DD = 128;
constexpr int BB = 32;
constexpr int NP = BB * BB;   // 1024 pairs
constexpr float FINF = 1e10f;

// K0: row squared-norms xn[2][BB*TT]
__global__ void xn_kernel(const float* __restrict__ xs,
                          const float* __restrict__ xt,
                          float* __restrict__ xn) {
  int idx = blockIdx.x * 256 + threadIdx.x;        // 0..6143
  if (idx >= 2 * BB * TT) return;
  int which = idx / (BB * TT);
  int row = idx - which * (BB * TT);
  const float* x = which ? xt : xs;
  const float4* xv = reinterpret_cast<const float4*>(x + (size_t)row * DD);
  float acc = 0.f;
#pragma unroll
  for (int k = 0; k < DD / 4; ++k) {
    float4 v = xv[k];
    acc = fmaf(v.x, v.x, acc);
    acc = fmaf(v.y, v.y, acc);
    acc = fmaf(v.z, v.z, acc);
    acc = fmaf(v.w, v.w, acc);
  }
  xn[idx] = acc;
}

// K1: one block per (pair p, tensor w). Compute C in LDS, then anti-diagonal DP.
__global__ __launch_bounds__(256, 2)
void sdtw_kernel(const float* __restrict__ xs,
                 const float* __restrict__ xt,
                 const float* __restrict__ xn,    // [2][BB*TT]
                 const float* __restrict__ gptr,
                 float* __restrict__ dtw) {       // [2][NP]
  __shared__ float Cs[TT][TT];       // 36864 B; DP read stride 95 words -> conflict-free
  __shared__ float xa_s[TT][33];     // padded: broadcast-friendly
  __shared__ float xb_s[TT][33];
  __shared__ float rbuf[3][TT];
  __shared__ float xna[TT];
  __shared__ float xnb[TT];

  const int p = blockIdx.x;
  const int w = blockIdx.y;
  const float* x = w ? xt : xs;
  const float* xnw = xn + w * (BB * TT);
  const int a = p >> 5;
  const int b = p & 31;
  const float* xa = x + (size_t)a * TT * DD;
  const float* xb = x + (size_t)b * TT * DD;
  const int tid = threadIdx.x;

  if (tid < TT) {
    xna[tid] = xnw[a * TT + tid];
    xnb[tid] = xnw[b * TT + tid];
  }

  const int ty = tid >> 4, tx = tid & 15;
  const int t0 = ty * 6, s0 = tx * 6;
  float acc[6][6];
#pragma unroll
  for (int r = 0; r < 6; ++r)
#pragma unroll
    for (int c = 0; c < 6; ++c) acc[r][c] = 0.f;

  for (int d0 = 0; d0 < DD; d0 += 32) {
    __syncthreads();   // protect LDS chunk reuse
#pragma unroll
    for (int it = 0; it < 12; ++it) {
      int idx = tid + it * 256;            // 3072 = 96*32 elements
      int t = idx >> 5, k = idx & 31;
      xa_s[t][k] = xa[t * DD + d0 + k];
      xb_s[t][k] = xb[t * DD + d0 + k];
    }
    __syncthreads();
#pragma unroll
    for (int k = 0; k < 32; ++k) {
      float av[6], bv[6];
#pragma unroll
      for (int r = 0; r < 6; ++r) av[r] = xa_s[t0 + r][k];
#pragma unroll
      for (int c = 0; c < 6; ++c) bv[c] = xb_s[s0 + c][k];
#pragma unroll
      for (int r = 0; r < 6; ++r)
#pragma unroll
        for (int c = 0; c < 6; ++c)
          acc[r][c] = fmaf(av[r], bv[c], acc[r][c]);
    }
  }
  __syncthreads();
#pragma unroll
  for (int r = 0; r < 6; ++r) {
    float xnar = xna[t0 + r];
#pragma unroll
    for (int c = 0; c < 6; ++c)
      Cs[t0 + r][s0 + c] = xnar + xnb[s0 + c] - 2.0f * acc[r][c];
  }

  const float gamma = gptr[0];
  const float rg = -1.0f / gamma;

  float* r2 = rbuf[0];
  float* r1 = rbuf[1];
  float* rn = rbuf[2];
  if (tid < TT) { rbuf[0][tid] = FINF; rbuf[1][tid] = FINF; }
  __syncthreads();

  for (int d = 0; d < 2 * TT - 1; ++d) {
    if (tid < TT) {
      const int i = tid;
      const int j = d - i;
      const bool valid = (j >= 0) && (j < TT);
      float up   = (i == 0) ? FINF : r1[i - 1];
      float left = r1[i];
      float diag = (i == 0) ? FINF : r2[i - 1];
      float smin;
      if (d == 0) {
        smin = 0.f;
      } else {
        float z0 = up * rg, z1 = left * rg, z2 = diag * rg;
        float m = fmaxf(fmaxf(z0, z1), z2);
        float s = expf(z0 - m) + expf(z1 - m) + expf(z2 - m);
        smin = -gamma * (m + logf(s));
      }
      int jc = j < 0 ? 0 : (j > TT - 1 ? TT - 1 : j);
      rn[i] = valid ? (Cs[i][jc] + smin) : FINF;
    }
    __syncthreads();
    float* tmp = r2; r2 = r1; r1 = rn; rn = tmp;
  }
  if (tid == TT - 1) dtw[w * NP + p] = r1[TT - 1];
}

// K2: means + normalized smooth-L1 (single block).
__global__ void reduce_kernel(const float* __restrict__ dtw,
                              float* __restrict__ out) {
  __shared__ double sh[256];
  const int tid = threadIdx.x;
  double ss = 0, st = 0;
  for (int k = tid; k < NP; k += 256) {
    ss += (double)dtw[k];
    st += (double)dtw[NP + k];
  }
  sh[tid] = ss; __syncthreads();
  for (int o = 128; o > 0; o >>= 1) { if (tid < o) sh[tid] += sh[tid + o]; __syncthreads(); }
  double sum_s = sh[0]; __syncthreads();
  sh[tid] = st; __syncthreads();
  for (int o = 128; o > 0; o >>= 1) { if (tid < o) sh[tid] += sh[tid + o]; __syncthreads(); }
  double sum_t = sh[0]; __syncthreads();

  float mean_s = (float)(sum_s / NP);
  float mean_t = (float)(sum_t / NP);

  double acc = 0;
  for (int k = tid; k < NP; k += 256) {
    float pred = dtw[k] / mean_s;
    float targ = dtw[NP + k] / mean_t;
    float d = pred - targ;
    float ad = fabsf(d);
    float v = ad < 1.f ? 0.5f * d * d : ad - 0.5f;
    acc += (double)v;
  }
  sh[tid] = acc; __syncthreads();
  for (int o = 128; o > 0; o >>= 1) { if (tid < o) sh[tid] += sh[tid + o]; __syncthreads(); }
  if (tid == 0) out[0] = (float)(sh[0] / NP);
}

extern "C" void kernel_launch(void* const* d_in, const int* in_sizes, int n_in,
                              void* d_out, int out_size, void* d_ws, size_t ws_size,
                              hipStream_t stream) {
  const float* student = (const float*)d_in[0];
  const float* teacher = (const float*)d_in[1];
  const float* gamma   = (const float*)d_in[2];
  float* ws  = (float*)d_ws;
  float* dtw = ws;             // [2*NP]
  float* xnb = ws + 2 * NP;    // [2*BB*TT]

  xn_kernel<<<24, 256, 0, stream>>>(student, teacher, xnb);
  sdtw_kernel<<<dim3(NP, 2), 256, 0, stream>>>(student, teacher, xnb, gamma, dtw);
  reduce_kernel<<<1, 256, 0, stream>>>(dtw, (float*)d_out);
}

// Round 2
// 299.576 us; speedup vs baseline: 1.0065x; 1.0065x over previous
//
#include <hip/hip_runtime.h>

// SoftDtwRkdDistance: B=32, T=96, D=128, f32 in, scalar f32 out.
// 2048 independent soft-DTW problems (1024 pairs x {student,teacher}).
// Per block: C matrix via register-tiled dot products (staged LDS chunks
// aliased inside Cs), then a single wave runs the 191-diagonal DP in
// registers with __shfl rotates (no barriers).

constexpr int TT = 96;
constexpr int DD = 128;
constexpr int BB = 32;
constexpr int NP = BB * BB;   // 1024 pairs
constexpr float FINF = 1e10f;

// K0: row squared-norms xn[2][BB*TT]
__global__ void xn_kernel(const float* __restrict__ xs,
                          const float* __restrict__ xt,
                          float* __restrict__ xn) {
  int idx = blockIdx.x * 256 + threadIdx.x;        // 0..6143
  if (idx >= 2 * BB * TT) return;
  int which = idx / (BB * TT);
  int row = idx - which * (BB * TT);
  const float* x = which ? xt : xs;
  const float4* xv = reinterpret_cast<const float4*>(x + (size_t)row * DD);
  float acc = 0.f;
#pragma unroll
  for (int k = 0; k < DD / 4; ++k) {
    float4 v = xv[k];
    acc = fmaf(v.x, v.x, acc);
    acc = fmaf(v.y, v.y, acc);
    acc = fmaf(v.z, v.z, acc);
    acc = fmaf(v.w, v.w, acc);
  }
  xn[idx] = acc;
}

// K1: one block per (pair p, tensor w).
__global__ __launch_bounds__(256, 4)
void sdtw_kernel(const float* __restrict__ xs,
                 const float* __restrict__ xt,
                 const float* __restrict__ xn,    // [2][BB*TT]
                 const float* __restrict__ gptr,
                 float* __restrict__ dtw) {       // [2][NP]
  __shared__ float Cs[TT * TT];      // 36864 B; staging aliases the front
  __shared__ float xna[TT];
  __shared__ float xnb[TT];

  const int p = blockIdx.x;
  const int w = blockIdx.y;
  const float* x = w ? xt : xs;
  const float* xnw = xn + w * (BB * TT);
  const int a = p >> 5;
  const int b = p & 31;
  const float* xa = x + (size_t)a * TT * DD;
  const float* xb = x + (size_t)b * TT * DD;
  const int tid = threadIdx.x;

  if (tid < TT) {
    xna[tid] = xnw[a * TT + tid];
    xnb[tid] = xnw[b * TT + tid];
  }

  // staging views inside Cs (disjoint in time from C storage)
  constexpr int SROW = 36;                 // floats per staged row, 16B-aligned
  float* xa_s = Cs;                        // [96][36] = 3456 floats
  float* xb_s = Cs + TT * SROW;            // 2*3456 = 6912 <= 9216 floats

  const int ty = tid >> 4, tx = tid & 15;
  const int t0 = ty * 6, s0 = tx * 6;
  float acc[6][6];
#pragma unroll
  for (int r = 0; r < 6; ++r)
#pragma unroll
    for (int c = 0; c < 6; ++c) acc[r][c] = 0.f;

  for (int d0 = 0; d0 < DD; d0 += 32) {
    __syncthreads();   // previous chunk's reads done before overwrite
    const float4* ga = reinterpret_cast<const float4*>(xa + d0);
    const float4* gb = reinterpret_cast<const float4*>(xb + d0);
    float4* sa = reinterpret_cast<float4*>(xa_s);
    float4* sb = reinterpret_cast<float4*>(xb_s);
#pragma unroll
    for (int it = 0; it < 3; ++it) {
      int idx = tid + it * 256;            // 0..767 float4s (96 rows x 8)
      int t = idx >> 3, k4 = idx & 7;
      sa[t * (SROW / 4) + k4] = ga[t * (DD / 4) + k4];
      sb[t * (SROW / 4) + k4] = gb[t * (DD / 4) + k4];
    }
    __syncthreads();
#pragma unroll
    for (int k4 = 0; k4 < 8; ++k4) {
      float4 av4[6], bv4[6];
#pragma unroll
      for (int r = 0; r < 6; ++r)
        av4[r] = reinterpret_cast<const float4*>(xa_s + (t0 + r) * SROW)[k4];
#pragma unroll
      for (int c = 0; c < 6; ++c)
        bv4[c] = reinterpret_cast<const float4*>(xb_s + (s0 + c) * SROW)[k4];
#pragma unroll
      for (int r = 0; r < 6; ++r)
#pragma unroll
        for (int c = 0; c < 6; ++c) {
          acc[r][c] = fmaf(av4[r].x, bv4[c].x, acc[r][c]);
          acc[r][c] = fmaf(av4[r].y, bv4[c].y, acc[r][c]);
          acc[r][c] = fmaf(av4[r].z, bv4[c].z, acc[r][c]);
          acc[r][c] = fmaf(av4[r].w, bv4[c].w, acc[r][c]);
        }
    }
  }
  __syncthreads();    // all staging reads complete; safe to overwrite with C
#pragma unroll
  for (int r = 0; r < 6; ++r) {
    float xr = xna[t0 + r];
#pragma unroll
    for (int c = 0; c < 6; ++c)
      Cs[(t0 + r) * TT + (s0 + c)] = xr + xnb[s0 + c] - 2.0f * acc[r][c];
  }
  __syncthreads();
  if (tid >= 64) return;   // waves 1..3 done; wave 0 runs the DP

  const float gamma = gptr[0];
  const float rg = -1.0f / gamma;
  const int lane = tid;
  const int lm1 = (lane + 63) & 63;        // rotate-by-1 source lane

  // lane handles cells i = lane (A) and i = 64+lane (B, valid lane<32)
  float A1 = FINF, B1 = FINF, A2 = FINF, B2 = FINF;

  for (int d = 0; d < 2 * TT - 1; ++d) {
    // C loads issued first: independent of the dependent chain
    int jA = d - lane;
    int jAc = jA < 0 ? 0 : (jA > TT - 1 ? TT - 1 : jA);
    float cA = Cs[lane * TT + jAc];
    int iB = 64 + lane;
    int jB = d - iB;
    int jBc = jB < 0 ? 0 : (jB > TT - 1 ? TT - 1 : jB);
    int iBc = iB > TT - 1 ? TT - 1 : iB;
    float cB = Cs[iBc * TT + jBc];

    float rA1 = __shfl(A1, lm1);
    float rB1 = __shfl(B1, lm1);
    float rA2 = __shfl(A2, lm1);
    float rB2 = __shfl(B2, lm1);
    const bool l0 = (lane == 0);
    float upA = l0 ? FINF : rA1;
    float dgA = l0 ? FINF : rA2;
    float upB = l0 ? rA1 : rB1;            // lane0's B-neighbor is cell 63 = A1@63
    float dgB = l0 ? rA2 : rB2;

    // softmin for A-cell (same expression order as reference)
    float z0 = upA * rg, z1 = A1 * rg, z2 = dgA * rg;
    float m = fmaxf(fmaxf(z0, z1), z2);
    float s = expf(z0 - m) + expf(z1 - m) + expf(z2 - m);
    float sminA = -gamma * (m + logf(s));
    if (d == 0) sminA = 0.f;
    // softmin for B-cell
    float y0 = upB * rg, y1 = B1 * rg, y2 = dgB * rg;
    float mb = fmaxf(fmaxf(y0, y1), y2);
    float sb2 = expf(y0 - mb) + expf(y1 - mb) + expf(y2 - mb);
    float sminB = -gamma * (mb + logf(sb2));

    bool vA = (jA >= 0) && (jA < TT);
    bool vB = (lane < 32) && (jB >= 0) && (jB < TT);
    float nA = vA ? cA + sminA : FINF;
    float nB = vB ? cB + sminB : FINF;
    A2 = A1; B2 = B1; A1 = nA; B1 = nB;
  }
  // cell (95,95) lives in B at lane 31 on the last diagonal
  if (lane == 31) dtw[w * NP + p] = B1;
}

// K2: means + normalized smooth-L1 (single block).
__global__ void reduce_kernel(const float* __restrict__ dtw,
                              float* __restrict__ out) {
  __shared__ double sh[256];
  const int tid = threadIdx.x;
  double ss = 0, st = 0;
  for (int k = tid; k < NP; k += 256) {
    ss += (double)dtw[k];
    st += (double)dtw[NP + k];
  }
  sh[tid] = ss; __syncthreads();
  for (int o = 128; o > 0; o >>= 1) { if (tid < o) sh[tid] += sh[tid + o]; __syncthreads(); }
  double sum_s = sh[0]; __syncthreads();
  sh[tid] = st; __syncthreads();
  for (int o = 128; o > 0; o >>= 1) { if (tid < o) sh[tid] += sh[tid + o]; __syncthreads(); }
  double sum_t = sh[0]; __syncthreads();

  float mean_s = (float)(sum_s / NP);
  float mean_t = (float)(sum_t / NP);

  double acc = 0;
  for (int k = tid; k < NP; k += 256) {
    float pred = dtw[k] / mean_s;
    float targ = dtw[NP + k] / mean_t;
    float d = pred - targ;
    float ad = fabsf(d);
    float v = ad < 1.f ? 0.5f * d * d : ad - 0.5f;
    acc += (double)v;
  }
  sh[tid] = acc; __syncthreads();
  for (int o = 128; o > 0; o >>= 1) { if (tid < o) sh[tid] += sh[tid + o]; __syncthreads(); }
  if (tid == 0) out[0] = (float)(sh[0] / NP);
}

extern "C" void kernel_launch(void* const* d_in, const int* in_sizes, int n_in,
                              void* d_out, int out_size, void* d_ws, size_t ws_size,
                              hipStream_t stream) {
  const float* student = (const float*)d_in[0];
  const float* teacher = (const float*)d_in[1];
  const float* gamma   = (const float*)d_in[2];
  float* ws  = (float*)d_ws;
  float* dtw = ws;             // [2*NP]
  float* xnb = ws + 2 * NP;    // [2*BB*TT]

  xn_kernel<<<24, 256, 0, stream>>>(student, teacher, xnb);
  sdtw_kernel<<<dim3(NP, 2), 256, 0, stream>>>(student, teacher, xnb, gamma, dtw);
  reduce_kernel<<<1, 256, 0, stream>>>(dtw, (float*)d_out);
}

// Round 3
// 183.826 us; speedup vs baseline: 1.6403x; 1.6297x over previous
//
#include <hip/hip_runtime.h>

// SoftDtwRkdDistance: B=32, T=96, D=128, f32 in, scalar f32 out.
// Soft-DTW is bit-exactly symmetric (dtw(a,b)==dtw(b,a): commutative swaps
// only) -> compute 528 unique pairs x {student,teacher} = 1056 blocks.
// Per block: C in LDS via register-tiled dot products (staging aliased inside
// Cs), then wave 0 runs the 191-diagonal DP in registers via __shfl rotates.

constexpr int TT = 96;
constexpr int DD = 128;
constexpr int BB = 32;
constexpr int NP = BB * BB;   // 1024 pairs
constexpr int NPAIR = BB * (BB + 1) / 2;  // 528
constexpr float FINF = 1e10f;

// K0: row squared-norms xn[2][BB*TT]
__global__ void xn_kernel(const float* __restrict__ xs,
                          const float* __restrict__ xt,
                          float* __restrict__ xn) {
  int idx = blockIdx.x * 256 + threadIdx.x;        // 0..6143
  if (idx >= 2 * BB * TT) return;
  int which = idx / (BB * TT);
  int row = idx - which * (BB * TT);
  const float* x = which ? xt : xs;
  const float4* xv = reinterpret_cast<const float4*>(x + (size_t)row * DD);
  float acc = 0.f;
#pragma unroll
  for (int k = 0; k < DD / 4; ++k) {
    float4 v = xv[k];
    acc = fmaf(v.x, v.x, acc);
    acc = fmaf(v.y, v.y, acc);
    acc = fmaf(v.z, v.z, acc);
    acc = fmaf(v.w, v.w, acc);
  }
  xn[idx] = acc;
}

__device__ __forceinline__ int tri_base(int a) {   // pairs with first index < a
  return a * BB - (a * (a - 1)) / 2;
}

// K1: one block per (unique pair, tensor w).
__global__ __launch_bounds__(256)
void sdtw_kernel(const float* __restrict__ xs,
                 const float* __restrict__ xt,
                 const float* __restrict__ xn,    // [2][BB*TT]
                 const float* __restrict__ gptr,
                 float* __restrict__ dtw) {       // [2][NP]
  __shared__ __align__(16) float Cs[TT * TT];     // 36864 B; staging aliases front
  __shared__ float xna[TT];
  __shared__ float xnb[TT];

  // decode triangular pair index -> (a, b), a <= b
  const int pr = blockIdx.x;
  int a = (int)((65.0f - sqrtf(4225.0f - 8.0f * (float)pr)) * 0.5f);
  while (tri_base(a + 1) <= pr) ++a;    // exact-boundary guards
  while (tri_base(a) > pr) --a;
  const int b = a + (pr - tri_base(a));

  const int w = blockIdx.y;
  const float* x = w ? xt : xs;
  const float* xnw = xn + w * (BB * TT);
  const float* xa = x + (size_t)a * TT * DD;
  const float* xb = x + (size_t)b * TT * DD;
  const int tid = threadIdx.x;

  if (tid < TT) {
    xna[tid] = xnw[a * TT + tid];
    xnb[tid] = xnw[b * TT + tid];
  }

  // staging views inside Cs (disjoint in time from C storage)
  constexpr int SROW = 36;                 // floats per staged row (16B-aligned rows)
  float* xa_s = Cs;                        // [96][36] = 3456 floats
  float* xb_s = Cs + TT * SROW;            // 6912 <= 9216 floats total

  // lane remap: each 16-lane quarter-wave spans 8 tx x 2 ty -> av4/bv4 <=2-way
  const int wv = tid >> 6;
  const int lane = tid & 63;
  const int tx = (lane & 7) + (wv & 1) * 8;      // 0..15
  const int ty = (lane >> 3) + (wv >> 1) * 8;    // 0..15
  const int t0 = ty * 6, s0 = tx * 6;

  float acc[6][6];
#pragma unroll
  for (int r = 0; r < 6; ++r)
#pragma unroll
    for (int c = 0; c < 6; ++c) acc[r][c] = 0.f;

  for (int d0 = 0; d0 < DD; d0 += 32) {
    __syncthreads();   // previous chunk's reads done before overwrite
    const float4* ga = reinterpret_cast<const float4*>(xa + d0);
    const float4* gb = reinterpret_cast<const float4*>(xb + d0);
    float4* sa = reinterpret_cast<float4*>(xa_s);
    float4* sb = reinterpret_cast<float4*>(xb_s);
#pragma unroll
    for (int it = 0; it < 3; ++it) {
      int idx = tid + it * 256;            // 0..767 float4s (96 rows x 8)
      int t = idx >> 3, k4 = idx & 7;
      sa[t * (SROW / 4) + k4] = ga[t * (DD / 4) + k4];
      sb[t * (SROW / 4) + k4] = gb[t * (DD / 4) + k4];
    }
    __syncthreads();
#pragma unroll
    for (int k4 = 0; k4 < 8; ++k4) {
      float4 av4[6], bv4[6];
#pragma unroll
      for (int r = 0; r < 6; ++r)
        av4[r] = reinterpret_cast<const float4*>(xa_s + (t0 + r) * SROW)[k4];
#pragma unroll
      for (int c = 0; c < 6; ++c)
        bv4[c] = reinterpret_cast<const float4*>(xb_s + (s0 + c) * SROW)[k4];
#pragma unroll
      for (int r = 0; r < 6; ++r)
#pragma unroll
        for (int c = 0; c < 6; ++c) {
          acc[r][c] = fmaf(av4[r].x, bv4[c].x, acc[r][c]);
          acc[r][c] = fmaf(av4[r].y, bv4[c].y, acc[r][c]);
          acc[r][c] = fmaf(av4[r].z, bv4[c].z, acc[r][c]);
          acc[r][c] = fmaf(av4[r].w, bv4[c].w, acc[r][c]);
        }
    }
  }
  __syncthreads();    // all staging reads complete; safe to overwrite with C
#pragma unroll
  for (int r = 0; r < 6; ++r) {
    float xr = xna[t0 + r];
#pragma unroll
    for (int c = 0; c < 6; ++c)
      Cs[(t0 + r) * TT + (s0 + c)] = xr + xnb[s0 + c] - 2.0f * acc[r][c];
  }
  __syncthreads();
  if (tid >= 64) return;   // waves 1..3 done; wave 0 runs the DP

  const float gamma = gptr[0];
  const float rg = -1.0f / gamma;
  const int lm1 = (lane + 63) & 63;        // rotate-by-1 source lane

  // lane handles cells i = lane (A) and i = 64+lane (B, valid lane<32)
  float A1 = FINF, B1 = FINF, A2 = FINF, B2 = FINF;

  for (int d = 0; d < 2 * TT - 1; ++d) {
    // C loads issued first: independent of the dependent chain.
    // Invalid lanes read Cs[0] (uniform broadcast -> no bank conflicts).
    int jA = d - lane;
    bool vA = (jA >= 0) && (jA < TT);
    float cA = Cs[vA ? lane * TT + jA : 0];
    int iB = 64 + lane;
    int jB = d - iB;
    bool vB = (lane < 32) && (jB >= 0) && (jB < TT);
    float cB = Cs[vB ? iB * TT + jB : 0];

    float rA1 = __shfl(A1, lm1);
    float rB1 = __shfl(B1, lm1);
    float rA2 = __shfl(A2, lm1);
    float rB2 = __shfl(B2, lm1);
    const bool l0 = (lane == 0);
    float upA = l0 ? FINF : rA1;
    float dgA = l0 ? FINF : rA2;
    float upB = l0 ? rA1 : rB1;            // lane0's B-neighbor is cell 63 = A1@63
    float dgB = l0 ? rA2 : rB2;

    // softmin for A-cell (same expression order as reference)
    float z0 = upA * rg, z1 = A1 * rg, z2 = dgA * rg;
    float m = fmaxf(fmaxf(z0, z1), z2);
    float s = expf(z0 - m) + expf(z1 - m) + expf(z2 - m);
    float sminA = -gamma * (m + logf(s));
    if (d == 0) sminA = 0.f;
    // softmin for B-cell
    float y0 = upB * rg, y1 = B1 * rg, y2 = dgB * rg;
    float mb = fmaxf(fmaxf(y0, y1), y2);
    float sb2 = expf(y0 - mb) + expf(y1 - mb) + expf(y2 - mb);
    float sminB = -gamma * (mb + logf(sb2));

    float nA = vA ? cA + sminA : FINF;
    float nB = vB ? cB + sminB : FINF;
    A2 = A1; B2 = B1; A1 = nA; B1 = nB;
  }
  // cell (95,95) lives in B at lane 31 on the last diagonal
  if (lane == 31) {
    float v = B1;
    dtw[w * NP + a * BB + b] = v;
    dtw[w * NP + b * BB + a] = v;    // bit-exact by transpose symmetry
  }
}

// K2: means + normalized smooth-L1 (single block).
__global__ void reduce_kernel(const float* __restrict__ dtw,
                              float* __restrict__ out) {
  __shared__ double sh[256];
  const int tid = threadIdx.x;
  double ss = 0, st = 0;
  for (int k = tid; k < NP; k += 256) {
    ss += (double)dtw[k];
    st += (double)dtw[NP + k];
  }
  sh[tid] = ss; __syncthreads();
  for (int o = 128; o > 0; o >>= 1) { if (tid < o) sh[tid] += sh[tid + o]; __syncthreads(); }
  double sum_s = sh[0]; __syncthreads();
  sh[tid] = st; __syncthreads();
  for (int o = 128; o > 0; o >>= 1) { if (tid < o) sh[tid] += sh[tid + o]; __syncthreads(); }
  double sum_t = sh[0]; __syncthreads();

  float mean_s = (float)(sum_s / NP);
  float mean_t = (float)(sum_t / NP);

  double acc = 0;
  for (int k = tid; k < NP; k += 256) {
    float pred = dtw[k] / mean_s;
    float targ = dtw[NP + k] / mean_t;
    float d = pred - targ;
    float ad = fabsf(d);
    float v = ad < 1.f ? 0.5f * d * d : ad - 0.5f;
    acc += (double)v;
  }
  sh[tid] = acc; __syncthreads();
  for (int o = 128; o > 0; o >>= 1) { if (tid < o) sh[tid] += sh[tid + o]; __syncthreads(); }
  if (tid == 0) out[0] = (float)(sh[0] / NP);
}

extern "C" void kernel_launch(void* const* d_in, const int* in_sizes, int n_in,
                              void* d_out, int out_size, void* d_ws, size_t ws_size,
                              hipStream_t stream) {
  const float* student = (const float*)d_in[0];
  const float* teacher = (const float*)d_in[1];
  const float* gamma   = (const float*)d_in[2];
  float* ws  = (float*)d_ws;
  float* dtw = ws;             // [2*NP]
  float* xnb = ws + 2 * NP;    // [2*BB*TT]

  xn_kernel<<<24, 256, 0, stream>>>(student, teacher, xnb);
  sdtw_kernel<<<dim3(NPAIR, 2), 256, 0, stream>>>(student, teacher, xnb, gamma, dtw);
  reduce_kernel<<<1, 256, 0, stream>>>(dtw, (float*)d_out);
}

// Round 4
// 143.492 us; speedup vs baseline: 2.1014x; 1.2811x over previous
//
#include <hip/hip_runtime.h>

// SoftDtwRkdDistance: B=32, T=96, D=128, f32 in, scalar f32 out.
// Split design:
//   K0 xn:  row squared-norms.
//   K1 csq: per (unique pair, tensor): C' = (xn_a+xn_b-2*dot)*rg2 written to
//           global in ANTI-DIAGONAL-MAJOR layout (rg2 = -log2e/gamma).
//   K2 dp:  one wave per problem, no LDS; 191-diagonal recurrence in
//           registers, softmin via raw v_exp_f32/v_log_f32 in the z''-domain.
//   K3 reduce: means + smooth-L1.
// Fallback: if ws too small for the 38 MB C buffer, run the round-3 fused kernel.

constexpr int TT = 96;
constexpr int DD = 128;
constexpr int BB = 32;
constexpr int NP = BB * BB;               // 1024
constexpr int NPAIR = BB * (BB + 1) / 2;  // 528
constexpr int NPROB = 2 * NPAIR;          // 1056
constexpr int CSZ = TT * TT;              // 9216 floats per problem
constexpr float FINF = 1e10f;
constexpr float LOG2E = 1.4426950408889634f;
constexpr float LN2 = 0.6931471805599453f;

__device__ __forceinline__ int tri_base(int a) {   // pairs with first index < a
  return a * BB - (a * (a - 1)) / 2;
}
__device__ __forceinline__ void tri_decode(int pr, int& a, int& b) {
  a = (int)((65.0f - sqrtf(4225.0f - 8.0f * (float)pr)) * 0.5f);
  while (tri_base(a + 1) <= pr) ++a;
  while (tri_base(a) > pr) --a;
  b = a + (pr - tri_base(a));
}

// K0: row squared-norms xn[2][BB*TT]
__global__ void xn_kernel(const float* __restrict__ xs,
                          const float* __restrict__ xt,
                          float* __restrict__ xn) {
  int idx = blockIdx.x * 256 + threadIdx.x;
  if (idx >= 2 * BB * TT) return;
  int which = idx / (BB * TT);
  int row = idx - which * (BB * TT);
  const float* x = which ? xt : xs;
  const float4* xv = reinterpret_cast<const float4*>(x + (size_t)row * DD);
  float acc = 0.f;
#pragma unroll
  for (int k = 0; k < DD / 4; ++k) {
    float4 v = xv[k];
    acc = fmaf(v.x, v.x, acc);
    acc = fmaf(v.y, v.y, acc);
    acc = fmaf(v.z, v.z, acc);
    acc = fmaf(v.w, v.w, acc);
  }
  xn[idx] = acc;
}

// K1: C' in diag-major global layout. One block per (unique pair, tensor).
__global__ __launch_bounds__(256)
void csq_kernel(const float* __restrict__ xs,
                const float* __restrict__ xt,
                const float* __restrict__ xn,
                const float* __restrict__ gptr,
                float* __restrict__ Cd) {
  __shared__ __align__(16) float Cs[CSZ];
  __shared__ float xna[TT];
  __shared__ float xnb[TT];

  const int pr = blockIdx.x;
  int a, b;
  tri_decode(pr, a, b);
  const int w = blockIdx.y;
  const float* x = w ? xt : xs;
  const float* xnw = xn + w * (BB * TT);
  const float* xa = x + (size_t)a * TT * DD;
  const float* xb = x + (size_t)b * TT * DD;
  const int tid = threadIdx.x;

  if (tid < TT) {
    xna[tid] = xnw[a * TT + tid];
    xnb[tid] = xnw[b * TT + tid];
  }

  constexpr int SROW = 36;
  float* xa_s = Cs;
  float* xb_s = Cs + TT * SROW;

  const int wv = tid >> 6;
  const int lane = tid & 63;
  const int tx = (lane & 7) + (wv & 1) * 8;
  const int ty = (lane >> 3) + (wv >> 1) * 8;
  const int t0 = ty * 6, s0 = tx * 6;

  float acc[6][6];
#pragma unroll
  for (int r = 0; r < 6; ++r)
#pragma unroll
    for (int c = 0; c < 6; ++c) acc[r][c] = 0.f;

  for (int d0 = 0; d0 < DD; d0 += 32) {
    __syncthreads();
    const float4* ga = reinterpret_cast<const float4*>(xa + d0);
    const float4* gb = reinterpret_cast<const float4*>(xb + d0);
    float4* sa = reinterpret_cast<float4*>(xa_s);
    float4* sb = reinterpret_cast<float4*>(xb_s);
#pragma unroll
    for (int it = 0; it < 3; ++it) {
      int idx = tid + it * 256;
      int t = idx >> 3, k4 = idx & 7;
      sa[t * (SROW / 4) + k4] = ga[t * (DD / 4) + k4];
      sb[t * (SROW / 4) + k4] = gb[t * (DD / 4) + k4];
    }
    __syncthreads();
#pragma unroll
    for (int k4 = 0; k4 < 8; ++k4) {
      float4 av4[6], bv4[6];
#pragma unroll
      for (int r = 0; r < 6; ++r)
        av4[r] = reinterpret_cast<const float4*>(xa_s + (t0 + r) * SROW)[k4];
#pragma unroll
      for (int c = 0; c < 6; ++c)
        bv4[c] = reinterpret_cast<const float4*>(xb_s + (s0 + c) * SROW)[k4];
#pragma unroll
      for (int r = 0; r < 6; ++r)
#pragma unroll
        for (int c = 0; c < 6; ++c) {
          acc[r][c] = fmaf(av4[r].x, bv4[c].x, acc[r][c]);
          acc[r][c] = fmaf(av4[r].y, bv4[c].y, acc[r][c]);
          acc[r][c] = fmaf(av4[r].z, bv4[c].z, acc[r][c]);
          acc[r][c] = fmaf(av4[r].w, bv4[c].w, acc[r][c]);
        }
    }
  }
  __syncthreads();
  const float rg2 = -LOG2E / gptr[0];
#pragma unroll
  for (int r = 0; r < 6; ++r) {
    float xr = xna[t0 + r];
#pragma unroll
    for (int c = 0; c < 6; ++c) {
      float cv = xr + xnb[s0 + c] - 2.0f * acc[r][c];   // exact ref C
      Cs[(t0 + r) * TT + (s0 + c)] = cv * rg2;          // pre-scaled
    }
  }
  __syncthreads();

  // write-out: diag-major, coalesced; wave wv handles diagonals d ≡ wv (mod 4)
  const size_t qb = (size_t)(w * NPAIR + pr) * CSZ;
  for (int d = wv; d < 2 * TT - 1; d += 4) {
    int s = d <= 95 ? 0 : d - 95;
    int len = 96 - (d <= 95 ? 95 - d : d - 95);
    int base = d <= 95 ? ((d * (d + 1)) >> 1)
                       : 4656 + (((d - 96) * (287 - d)) >> 1);
    if (lane < len) {
      int i = s + lane;
      Cd[qb + base + lane] = Cs[i * TT + (d - i)];
    }
    if (len > 64 && lane < len - 64) {
      int i = s + 64 + lane;
      Cd[qb + base + 64 + lane] = Cs[i * TT + (d - i)];
    }
  }
}

// K2: DP. One wave per problem q = w*528 + pr. No LDS.
__global__ __launch_bounds__(64)
void dp_kernel(const float* __restrict__ Cd,
               const float* __restrict__ gptr,
               float* __restrict__ dtw) {
  const int q = blockIdx.x;
  const int l = threadIdx.x;
  const float gamma = gptr[0];
  const float rg2 = -LOG2E / gamma;
  const float NEGI = FINF * rg2;          // invalid cell in z''-domain
  const float* cb = Cd + (size_t)q * CSZ;
  const int lp1 = (l + 1) & 63, lm1 = (l + 63) & 63;

  // d=0 peel: r(0,0)'' = C''(0,0)
  float A1 = (l == 0) ? cb[0] : NEGI;
  float B1 = NEGI, A2 = NEGI, B2 = NEGI;

  int base = 1;
  for (int d = 1; d < 2 * TT - 1; ++d) {
    const int len = 96 - (d <= 95 ? 95 - d : d - 95);
    // loads independent of the dependent chain -> issue early
    float cA = cb[base + l];
    float cB = cb[base + 64 + l];

    float upA, upB, lfA, lfB, dgA, dgB;
    if (d <= 95) {                 // neighbor offsets (-1, 0, -1)
      float rA1 = __shfl(A1, lm1), rB1 = __shfl(B1, lm1);
      float rA2 = __shfl(A2, lm1), rB2 = __shfl(B2, lm1);
      bool l0 = (l == 0);
      upA = l0 ? NEGI : rA1;  dgA = l0 ? NEGI : rA2;
      upB = l0 ? rA1 : rB1;   dgB = l0 ? rA2 : rB2;  // lane0: rA1 = A1@63
      lfA = A1; lfB = B1;
    } else if (d == 96) {          // offsets (0, +1, 0)
      float rA1 = __shfl(A1, lp1), rB1 = __shfl(B1, lp1);
      bool l63 = (l == 63);
      lfA = l63 ? rB1 : rA1;  lfB = rB1;             // lane63: rB1 = B1@0
      upA = A1; upB = B1; dgA = A2; dgB = B2;
    } else {                       // offsets (0, +1, +1)
      float rA1 = __shfl(A1, lp1), rB1 = __shfl(B1, lp1);
      float rA2 = __shfl(A2, lp1), rB2 = __shfl(B2, lp1);
      bool l63 = (l == 63);
      lfA = l63 ? rB1 : rA1;  lfB = rB1;
      dgA = l63 ? rB2 : rA2;  dgB = rB2;
      upA = A1; upB = B1;
    }

    // softmin in z''-domain: r'' = C'' + m + log2(sum exp2(z-m)), order (up,left,diag)
    float m = fmaxf(fmaxf(upA, lfA), dgA);
    float s = __builtin_amdgcn_exp2f(upA - m) + __builtin_amdgcn_exp2f(lfA - m)
            + __builtin_amdgcn_exp2f(dgA - m);
    float nA = cA + (m + __builtin_amdgcn_logf(s));
    float mB = fmaxf(fmaxf(upB, lfB), dgB);
    float sB = __builtin_amdgcn_exp2f(upB - mB) + __builtin_amdgcn_exp2f(lfB - mB)
             + __builtin_amdgcn_exp2f(dgB - mB);
    float nB = cB + (mB + __builtin_amdgcn_logf(sB));

    A2 = A1; B2 = B1;
    A1 = (l < len) ? nA : NEGI;
    B1 = (64 + l < len) ? nB : NEGI;
    base += len;
  }
  // cell (95,95) = position 0 of diag 190 -> lane 0, A1
  if (l == 0) {
    int w = q >= NPAIR ? 1 : 0;
    int pr = q - w * NPAIR;
    int a, b;
    tri_decode(pr, a, b);
    float v = A1 * (-gamma * LN2);       // back to r-domain
    dtw[w * NP + a * BB + b] = v;
    dtw[w * NP + b * BB + a] = v;
  }
}

// ---------------- Fallback fused kernel (round-3, proven) ----------------
__global__ __launch_bounds__(256)
void sdtw_fused_kernel(const float* __restrict__ xs,
                       const float* __restrict__ xt,
                       const float* __restrict__ xn,
                       const float* __restrict__ gptr,
                       float* __restrict__ dtw) {
  __shared__ __align__(16) float Cs[TT * TT];
  __shared__ float xna[TT];
  __shared__ float xnb[TT];

  const int pr = blockIdx.x;
  int a, b;
  tri_decode(pr, a, b);
  const int w = blockIdx.y;
  const float* x = w ? xt : xs;
  const float* xnw = xn + w * (BB * TT);
  const float* xa = x + (size_t)a * TT * DD;
  const float* xb = x + (size_t)b * TT * DD;
  const int tid = threadIdx.x;

  if (tid < TT) {
    xna[tid] = xnw[a * TT + tid];
    xnb[tid] = xnw[b * TT + tid];
  }
  constexpr int SROW = 36;
  float* xa_s = Cs;
  float* xb_s = Cs + TT * SROW;
  const int wv = tid >> 6;
  const int lane = tid & 63;
  const int tx = (lane & 7) + (wv & 1) * 8;
  const int ty = (lane >> 3) + (wv >> 1) * 8;
  const int t0 = ty * 6, s0 = tx * 6;
  float acc[6][6];
#pragma unroll
  for (int r = 0; r < 6; ++r)
#pragma unroll
    for (int c = 0; c < 6; ++c) acc[r][c] = 0.f;
  for (int d0 = 0; d0 < DD; d0 += 32) {
    __syncthreads();
    const float4* ga = reinterpret_cast<const float4*>(xa + d0);
    const float4* gb = reinterpret_cast<const float4*>(xb + d0);
    float4* sa = reinterpret_cast<float4*>(xa_s);
    float4* sb = reinterpret_cast<float4*>(xb_s);
#pragma unroll
    for (int it = 0; it < 3; ++it) {
      int idx = tid + it * 256;
      int t = idx >> 3, k4 = idx & 7;
      sa[t * (SROW / 4) + k4] = ga[t * (DD / 4) + k4];
      sb[t * (SROW / 4) + k4] = gb[t * (DD / 4) + k4];
    }
    __syncthreads();
#pragma unroll
    for (int k4 = 0; k4 < 8; ++k4) {
      float4 av4[6], bv4[6];
#pragma unroll
      for (int r = 0; r < 6; ++r)
        av4[r] = reinterpret_cast<const float4*>(xa_s + (t0 + r) * SROW)[k4];
#pragma unroll
      for (int c = 0; c < 6; ++c)
        bv4[c] = reinterpret_cast<const float4*>(xb_s + (s0 + c) * SROW)[k4];
#pragma unroll
      for (int r = 0; r < 6; ++r)
#pragma unroll
        for (int c = 0; c < 6; ++c) {
          acc[r][c] = fmaf(av4[r].x, bv4[c].x, acc[r][c]);
          acc[r][c] = fmaf(av4[r].y, bv4[c].y, acc[r][c]);
          acc[r][c] = fmaf(av4[r].z, bv4[c].z, acc[r][c]);
          acc[r][c] = fmaf(av4[r].w, bv4[c].w, acc[r][c]);
        }
    }
  }
  __syncthreads();
#pragma unroll
  for (int r = 0; r < 6; ++r) {
    float xr = xna[t0 + r];
#pragma unroll
    for (int c = 0; c < 6; ++c)
      Cs[(t0 + r) * TT + (s0 + c)] = xr + xnb[s0 + c] - 2.0f * acc[r][c];
  }
  __syncthreads();
  if (tid >= 64) return;

  const float gamma = gptr[0];
  const float rg = -1.0f / gamma;
  const int lm1 = (lane + 63) & 63;
  float A1 = FINF, B1 = FINF, A2 = FINF, B2 = FINF;
  for (int d = 0; d < 2 * TT - 1; ++d) {
    int jA = d - lane;
    bool vA = (jA >= 0) && (jA < TT);
    float cA = Cs[vA ? lane * TT + jA : 0];
    int iB = 64 + lane;
    int jB = d - iB;
    bool vB = (lane < 32) && (jB >= 0) && (jB < TT);
    float cB = Cs[vB ? iB * TT + jB : 0];
    float rA1 = __shfl(A1, lm1);
    float rB1 = __shfl(B1, lm1);
    float rA2 = __shfl(A2, lm1);
    float rB2 = __shfl(B2, lm1);
    const bool l0 = (lane == 0);
    float upA = l0 ? FINF : rA1;
    float dgA = l0 ? FINF : rA2;
    float upB = l0 ? rA1 : rB1;
    float dgB = l0 ? rA2 : rB2;
    float z0 = upA * rg, z1 = A1 * rg, z2 = dgA * rg;
    float m = fmaxf(fmaxf(z0, z1), z2);
    float s = expf(z0 - m) + expf(z1 - m) + expf(z2 - m);
    float sminA = -gamma * (m + logf(s));
    if (d == 0) sminA = 0.f;
    float y0 = upB * rg, y1 = B1 * rg, y2 = dgB * rg;
    float mb = fmaxf(fmaxf(y0, y1), y2);
    float sb2 = expf(y0 - mb) + expf(y1 - mb) + expf(y2 - mb);
    float sminB = -gamma * (mb + logf(sb2));
    float nA = vA ? cA + sminA : FINF;
    float nB = vB ? cB + sminB : FINF;
    A2 = A1; B2 = B1; A1 = nA; B1 = nB;
  }
  if (lane == 31) {
    float v = B1;
    dtw[w * NP + a * BB + b] = v;
    dtw[w * NP + b * BB + a] = v;
  }
}

// K3: means + normalized smooth-L1 (single block).
__global__ void reduce_kernel(const float* __restrict__ dtw,
                              float* __restrict__ out) {
  __shared__ double sh[256];
  const int tid = threadIdx.x;
  double ss = 0, st = 0;
  for (int k = tid; k < NP; k += 256) {
    ss += (double)dtw[k];
    st += (double)dtw[NP + k];
  }
  sh[tid] = ss; __syncthreads();
  for (int o = 128; o > 0; o >>= 1) { if (tid < o) sh[tid] += sh[tid + o]; __syncthreads(); }
  double sum_s = sh[0]; __syncthreads();
  sh[tid] = st; __syncthreads();
  for (int o = 128; o > 0; o >>= 1) { if (tid < o) sh[tid] += sh[tid + o]; __syncthreads(); }
  double sum_t = sh[0]; __syncthreads();

  float mean_s = (float)(sum_s / NP);
  float mean_t = (float)(sum_t / NP);

  double acc = 0;
  for (int k = tid; k < NP; k += 256) {
    float pred = dtw[k] / mean_s;
    float targ = dtw[NP + k] / mean_t;
    float d = pred - targ;
    float ad = fabsf(d);
    float v = ad < 1.f ? 0.5f * d * d : ad - 0.5f;
    acc += (double)v;
  }
  sh[tid] = acc; __syncthreads();
  for (int o = 128; o > 0; o >>= 1) { if (tid < o) sh[tid] += sh[tid + o]; __syncthreads(); }
  if (tid == 0) out[0] = (float)(sh[0] / NP);
}

extern "C" void kernel_launch(void* const* d_in, const int* in_sizes, int n_in,
                              void* d_out, int out_size, void* d_ws, size_t ws_size,
                              hipStream_t stream) {
  const float* student = (const float*)d_in[0];
  const float* teacher = (const float*)d_in[1];
  const float* gamma   = (const float*)d_in[2];
  float* ws = (float*)d_ws;

  const size_t cd_floats = (size_t)NPROB * CSZ;              // 9,732,096
  const size_t need = (cd_floats + 2 * NP + 2 * BB * TT) * sizeof(float);

  if (ws_size >= need) {
    float* Cd  = ws;
    float* dtw = ws + cd_floats;
    float* xnb = dtw + 2 * NP;
    xn_kernel<<<24, 256, 0, stream>>>(student, teacher, xnb);
    csq_kernel<<<dim3(NPAIR, 2), 256, 0, stream>>>(student, teacher, xnb, gamma, Cd);
    dp_kernel<<<NPROB, 64, 0, stream>>>(Cd, gamma, dtw);
    reduce_kernel<<<1, 256, 0, stream>>>(dtw, (float*)d_out);
  } else {
    float* dtw = ws;
    float* xnb = ws + 2 * NP;
    xn_kernel<<<24, 256, 0, stream>>>(student, teacher, xnb);
    sdtw_fused_kernel<<<dim3(NPAIR, 2), 256, 0, stream>>>(student, teacher, xnb, gamma, dtw);
    reduce_kernel<<<1, 256, 0, stream>>>(dtw, (float*)d_out);
  }
}